// Round 2
// baseline (2360.586 us; speedup 1.0000x reference)
//
#include <hip/hip_runtime.h>
#include <hip/hip_bf16.h>

#define N_NODES 50000
#define N_EDGES 800000
#define IN_DIM 64
#define HID_DIM 128
#define OUT_DIM 64

// ---- all scratch in device globals: no dependence on ws_size ----
__device__ int g_in_f32;   // 1 if float inputs are f32, 0 if bf16
__device__ int g_is64;     // 1 if edge_index is int64, 0 if int32
__device__ int g_src[N_EDGES];
__device__ int g_dst[N_EDGES];
__device__ float g_deg[N_NODES];
__device__ float g_dinv[N_NODES];
__device__ __align__(16) float g_hs1[(size_t)N_NODES * HID_DIM];   // 25.6 MB (also reused as h)
__device__ __align__(16) float g_agg1[(size_t)N_NODES * HID_DIM];  // 25.6 MB (reused as hs2|agg2)

// dtype-adaptive load of a "float" input (f32 or bf16 per flag)
__device__ __forceinline__ float loadx(const void* p, int i, int f32) {
    if (f32) return ((const float*)p)[i];
    unsigned int u = ((unsigned int)((const unsigned short*)p)[i]) << 16;
    return __uint_as_float(u);
}

// ---- detect input dtype + edge index width from data (deterministic per call) ----
__global__ void detect_kernel(const unsigned short* __restrict__ zw,
                              const unsigned int* __restrict__ ew, int E) {
    __shared__ int s_f32, s_nz;
    if (threadIdx.x == 0) { s_f32 = 0; s_nz = 0; }
    __syncthreads();
    // f32 inputs: even-indexed 16-bit words are low halves of f32 (random mantissa
    // bits) -> bf16-exponent field == 0xFF with p=1/256. bf16 inputs: finite values,
    // exponent never 0xFF. Sample 16384 even words of z.
    int hit = 0;
    for (int k = 0; k < 64; k++) {
        int i = 2 * ((threadIdx.x * 64 + k) * 97);  // even, max < 3.2M
        unsigned short w = zw[i];
        if (((w >> 7) & 0xFF) == 0xFF) hit = 1;
    }
    if (hit) atomicOr(&s_f32, 1);
    // int64 edge_index: odd 32-bit words are high halves of values < 2^31 -> all 0.
    int nz = 0;
    int step = E / 4096;  // 195
    for (int k = 0; k < 4; k++) {
        int idx = 1 + 2 * ((threadIdx.x * 4 + k) * step);  // odd, max < 400k < 1.6M
        if (ew[idx] != 0) nz = 1;
    }
    if (nz) atomicOr(&s_nz, 1);
    __syncthreads();
    if (threadIdx.x == 0) { g_in_f32 = s_f32; g_is64 = (s_nz == 0) ? 1 : 0; }
}

// ---- normalize edge_index into int32 g_src/g_dst; zero g_deg ----
__global__ void convert_kernel(const void* __restrict__ ei, int E) {
    int e = blockIdx.x * blockDim.x + threadIdx.x;
    if (e < E) {
        if (g_is64) {
            const long long* p = (const long long*)ei;
            g_src[e] = (int)p[e];
            g_dst[e] = (int)p[E + e];
        } else {
            const int* p = (const int*)ei;
            g_src[e] = p[e];
            g_dst[e] = p[E + e];
        }
    }
    if (e < N_NODES) g_deg[e] = 0.f;
}

__global__ void deg_kernel(int E) {
    int i = blockIdx.x * blockDim.x + threadIdx.x;
    if (i < E) atomicAdd(&g_deg[g_dst[i]], 1.0f);
}

__global__ void dinv_kernel(int N) {
    int i = blockIdx.x * blockDim.x + threadIdx.x;
    if (i < N) g_dinv[i] = rsqrtf(g_deg[i] + 1.0f);  // +1 = self loop
}

// ---- hs1[row,:] = (z[row,:] @ W1) * dinv[row]; agg1 = hs1 (self-loop term) ----
__global__ void gemm1_kernel(const void* __restrict__ z, const void* __restrict__ W1, int N) {
    __shared__ float Ws[IN_DIM * HID_DIM];  // 32 KB
    __shared__ float zs[2 * IN_DIM];
    int t = threadIdx.x;
    int f32 = g_in_f32;
    for (int i = t; i < IN_DIM * HID_DIM; i += 256) Ws[i] = loadx(W1, i, f32);
    int row0 = blockIdx.x * 2;
    if (t < 2 * IN_DIM) {
        int r = row0 + (t >> 6);
        zs[t] = (r < N) ? loadx(z, r * IN_DIM + (t & (IN_DIM - 1)), f32) : 0.f;
    }
    __syncthreads();
    int r = t >> 7;
    int col = t & 127;
    int row = row0 + r;
    if (row >= N) return;
    float acc = 0.f;
#pragma unroll
    for (int k = 0; k < IN_DIM; k++) acc = fmaf(zs[r * IN_DIM + k], Ws[k * HID_DIM + col], acc);
    float v = acc * g_dinv[row];
    int o = row * HID_DIM + col;
    g_hs1[o] = v;
    g_agg1[o] = v;
}

// ---- agg1[dst,:] += hs1[src,:]  (32 threads/edge, float4) ----
__global__ void edge_agg1_kernel(int E) {
    int idx = blockIdx.x * blockDim.x + threadIdx.x;
    if (idx >= E * 32) return;
    int e = idx >> 5;
    int f = (idx & 31) << 2;
    int s = g_src[e], d = g_dst[e];
    float4 v = *(const float4*)&g_hs1[s * HID_DIM + f];
    float* p = &g_agg1[d * HID_DIM + f];
    atomicAdd(p + 0, v.x);
    atomicAdd(p + 1, v.y);
    atomicAdd(p + 2, v.z);
    atomicAdd(p + 3, v.w);
}

// ---- h = relu(agg1 * dinv[row] + b1)  (h overwrites g_hs1) ----
__global__ void relu1_kernel(const void* __restrict__ b1, int N) {
    int idx = blockIdx.x * blockDim.x + threadIdx.x;
    if (idx >= N * HID_DIM) return;
    int row = idx >> 7;
    int col = idx & 127;
    float v = g_agg1[idx] * g_dinv[row] + loadx(b1, col, g_in_f32);
    g_hs1[idx] = v > 0.f ? v : 0.f;
}

// ---- hs2[row,:] = (h[row,:] @ W2) * dinv[row]; agg2 = hs2. hs2/agg2 live in g_agg1. ----
__global__ void gemm2_kernel(const void* __restrict__ W2, int N) {
    __shared__ float Ws[HID_DIM * OUT_DIM];  // 32 KB
    __shared__ float hsh[4 * HID_DIM];
    int t = threadIdx.x;
    int f32 = g_in_f32;
    for (int i = t; i < HID_DIM * OUT_DIM; i += 256) Ws[i] = loadx(W2, i, f32);
    int row0 = blockIdx.x * 4;
    for (int i = t; i < 4 * HID_DIM; i += 256) {
        int r = row0 + (i >> 7);
        hsh[i] = (r < N) ? g_hs1[r * HID_DIM + (i & (HID_DIM - 1))] : 0.f;
    }
    __syncthreads();
    int r = t >> 6;
    int col = t & 63;
    int row = row0 + r;
    if (row >= N) return;
    float acc = 0.f;
#pragma unroll
    for (int k = 0; k < HID_DIM; k++) acc = fmaf(hsh[r * HID_DIM + k], Ws[k * OUT_DIM + col], acc);
    float v = acc * g_dinv[row];
    int o = row * OUT_DIM + col;
    float* hs2 = g_agg1;
    float* agg2 = g_agg1 + (size_t)N_NODES * OUT_DIM;
    hs2[o] = v;
    agg2[o] = v;
}

// ---- agg2[dst,:] += hs2[src,:]  (16 threads/edge, float4) ----
__global__ void edge_agg2_kernel(int E) {
    int idx = blockIdx.x * blockDim.x + threadIdx.x;
    if (idx >= E * 16) return;
    int e = idx >> 4;
    int f = (idx & 15) << 2;
    int s = g_src[e], d = g_dst[e];
    const float* hs2 = g_agg1;
    float* agg2 = g_agg1 + (size_t)N_NODES * OUT_DIM;
    float4 v = *(const float4*)&hs2[s * OUT_DIM + f];
    float* p = &agg2[d * OUT_DIM + f];
    atomicAdd(p + 0, v.x);
    atomicAdd(p + 1, v.y);
    atomicAdd(p + 2, v.z);
    atomicAdd(p + 3, v.w);
}

// ---- out = (agg2 * dinv[row] + b2), stored as f32 or bf16 matching input dtype ----
__global__ void final_kernel(const void* __restrict__ b2, void* __restrict__ out, int N) {
    int idx = blockIdx.x * blockDim.x + threadIdx.x;
    if (idx >= N * OUT_DIM) return;
    int row = idx >> 6;
    int col = idx & 63;
    int f32 = g_in_f32;
    const float* agg2 = g_agg1 + (size_t)N_NODES * OUT_DIM;
    float v = agg2[idx] * g_dinv[row] + loadx(b2, col, f32);
    if (f32) {
        ((float*)out)[idx] = v;
    } else {
        ((__hip_bfloat16*)out)[idx] = __float2bfloat16(v);
    }
}

extern "C" void kernel_launch(void* const* d_in, const int* in_sizes, int n_in,
                              void* d_out, int out_size, void* d_ws, size_t ws_size,
                              hipStream_t stream) {
    const void* z  = d_in[0];
    const void* ei = d_in[1];
    const void* W1 = d_in[2];
    const void* b1 = d_in[3];
    const void* W2 = d_in[4];
    const void* b2 = d_in[5];

    const int N = in_sizes[0] / IN_DIM;  // 50000
    const int E = in_sizes[1] / 2;       // 800000

    detect_kernel<<<1, 256, 0, stream>>>((const unsigned short*)z, (const unsigned int*)ei, E);
    convert_kernel<<<(E + 255) / 256, 256, 0, stream>>>(ei, E);
    deg_kernel<<<(E + 255) / 256, 256, 0, stream>>>(E);
    dinv_kernel<<<(N + 255) / 256, 256, 0, stream>>>(N);

    gemm1_kernel<<<(N + 1) / 2, 256, 0, stream>>>(z, W1, N);
    edge_agg1_kernel<<<(E * 32 + 255) / 256, 256, 0, stream>>>(E);
    relu1_kernel<<<(N * HID_DIM + 255) / 256, 256, 0, stream>>>(b1, N);

    gemm2_kernel<<<(N + 3) / 4, 256, 0, stream>>>(W2, N);
    edge_agg2_kernel<<<(E * 16 + 255) / 256, 256, 0, stream>>>(E);
    final_kernel<<<(N * OUT_DIM + 255) / 256, 256, 0, stream>>>(b2, d_out, N);
}

// Round 3
// 674.368 us; speedup vs baseline: 3.5004x; 3.5004x over previous
//
#include <hip/hip_runtime.h>
#include <hip/hip_bf16.h>

#define N_NODES 50000
#define N_EDGES 800000
#define IN_DIM 64
#define HID_DIM 128
#define OUT_DIM 64
#define SCAN_T 1024
#define CHUNK ((N_NODES + SCAN_T - 1) / SCAN_T)  // 49

// ---- device-global scratch (no ws_size dependence) ----
__device__ int g_in_f32;
__device__ int g_is64;
__device__ int g_src[N_EDGES];
__device__ int g_dst[N_EDGES];
__device__ int g_csr[N_EDGES];
__device__ int g_deg[N_NODES];
__device__ int g_rowptr[N_NODES + 1];
__device__ int g_cursor[N_NODES];
__device__ float g_dinv[N_NODES];
__device__ __align__(16) float g_hs1[(size_t)N_NODES * HID_DIM];   // hs1, later hs2 (N*64)
__device__ __align__(16) float g_agg1[(size_t)N_NODES * HID_DIM];  // h after layer-1

__device__ __forceinline__ float loadx(const void* p, int i, int f32) {
    if (f32) return ((const float*)p)[i];
    unsigned int u = ((unsigned int)((const unsigned short*)p)[i]) << 16;
    return __uint_as_float(u);
}

// ---- dtype / index-width detection (data-driven, deterministic) ----
__global__ void detect_kernel(const unsigned short* __restrict__ zw,
                              const unsigned int* __restrict__ ew, int E) {
    __shared__ int s_f32, s_nz;
    if (threadIdx.x == 0) { s_f32 = 0; s_nz = 0; }
    __syncthreads();
    int hit = 0;
    for (int k = 0; k < 64; k++) {
        int i = 2 * ((threadIdx.x * 64 + k) * 97);
        if (((zw[i] >> 7) & 0xFF) == 0xFF) hit = 1;
    }
    if (hit) atomicOr(&s_f32, 1);
    int nz = 0;
    int step = E / 4096;
    for (int k = 0; k < 4; k++) {
        int idx = 1 + 2 * ((threadIdx.x * 4 + k) * step);
        if (ew[idx] != 0) nz = 1;
    }
    if (nz) atomicOr(&s_nz, 1);
    __syncthreads();
    if (threadIdx.x == 0) { g_in_f32 = s_f32; g_is64 = (s_nz == 0) ? 1 : 0; }
}

// ---- normalize edge_index to int32; zero degree ----
__global__ void convert_kernel(const void* __restrict__ ei, int E) {
    int e = blockIdx.x * blockDim.x + threadIdx.x;
    if (e < E) {
        if (g_is64) {
            const long long* p = (const long long*)ei;
            g_src[e] = (int)p[e];
            g_dst[e] = (int)p[E + e];
        } else {
            const int* p = (const int*)ei;
            g_src[e] = p[e];
            g_dst[e] = p[E + e];
        }
    }
    if (e < N_NODES) g_deg[e] = 0;
}

__global__ void deg_kernel(int E) {
    int i = blockIdx.x * blockDim.x + threadIdx.x;
    if (i < E) atomicAdd(&g_deg[g_dst[i]], 1);
}

// ---- single-block exclusive scan of deg -> rowptr + cursor; dinv fused ----
__global__ __launch_bounds__(SCAN_T) void scan_kernel(int N, int E) {
    __shared__ int part[SCAN_T];
    int t = threadIdx.x;
    int beg = t * CHUNK, end = min(beg + CHUNK, N);
    int s = 0;
    for (int i = beg; i < end; i++) s += g_deg[i];
    part[t] = s;
    __syncthreads();
    for (int off = 1; off < SCAN_T; off <<= 1) {
        int v = (t >= off) ? part[t - off] : 0;
        __syncthreads();
        part[t] += v;
        __syncthreads();
    }
    int base = (t == 0) ? 0 : part[t - 1];
    for (int i = beg; i < end; i++) {
        g_rowptr[i] = base;
        g_cursor[i] = base;
        base += g_deg[i];
        g_dinv[i] = rsqrtf((float)g_deg[i] + 1.0f);  // +1 = self loop
    }
    if (t == SCAN_T - 1) g_rowptr[N] = E;
}

// ---- scatter edges into CSR buckets by dst ----
__global__ void scatter_kernel(int E) {
    int e = blockIdx.x * blockDim.x + threadIdx.x;
    if (e < E) {
        int pos = atomicAdd(&g_cursor[g_dst[e]], 1);
        g_csr[pos] = g_src[e];
    }
}

// ---- hs1[row,:] = (z[row,:] @ W1) * dinv[row] ----
__global__ void gemm1_kernel(const void* __restrict__ z, const void* __restrict__ W1, int N) {
    __shared__ float Ws[IN_DIM * HID_DIM];  // 32 KB
    __shared__ float zs[2 * IN_DIM];
    int t = threadIdx.x;
    int f32 = g_in_f32;
    for (int i = t; i < IN_DIM * HID_DIM; i += 256) Ws[i] = loadx(W1, i, f32);
    int row0 = blockIdx.x * 2;
    if (t < 2 * IN_DIM) {
        int r = row0 + (t >> 6);
        zs[t] = (r < N) ? loadx(z, r * IN_DIM + (t & (IN_DIM - 1)), f32) : 0.f;
    }
    __syncthreads();
    int r = t >> 7;
    int col = t & 127;
    int row = row0 + r;
    if (row >= N) return;
    float acc = 0.f;
#pragma unroll
    for (int k = 0; k < IN_DIM; k++) acc = fmaf(zs[r * IN_DIM + k], Ws[k * HID_DIM + col], acc);
    g_hs1[row * HID_DIM + col] = acc * g_dinv[row];
}

// ---- layer-1 aggregation: wave per node, float2/lane; fused relu epilogue -> h ----
__global__ void agg1_kernel(const void* __restrict__ b1, int N) {
    int wid = (blockIdx.x * blockDim.x + threadIdx.x) >> 6;
    if (wid >= N) return;
    int lane = threadIdx.x & 63;
    const float2* hs = (const float2*)g_hs1;  // row = 64 float2
    int off = lane;
    float2 acc = hs[wid * 64 + off];          // self-loop term
    float ax2 = 0.f, ay2 = 0.f;
    int beg = g_rowptr[wid], end = g_rowptr[wid + 1];
    int e = beg;
    for (; e + 2 <= end; e += 2) {
        int s0 = g_csr[e], s1 = g_csr[e + 1];
        float2 v0 = hs[s0 * 64 + off];
        float2 v1 = hs[s1 * 64 + off];
        acc.x += v0.x; acc.y += v0.y;
        ax2 += v1.x;  ay2 += v1.y;
    }
    if (e < end) {
        float2 v0 = hs[g_csr[e] * 64 + off];
        acc.x += v0.x; acc.y += v0.y;
    }
    acc.x += ax2; acc.y += ay2;
    float dn = g_dinv[wid];
    int f32 = g_in_f32;
    int col = lane * 2;
    float vx = acc.x * dn + loadx(b1, col, f32);
    float vy = acc.y * dn + loadx(b1, col + 1, f32);
    vx = vx > 0.f ? vx : 0.f;
    vy = vy > 0.f ? vy : 0.f;
    ((float2*)g_agg1)[wid * 64 + off] = make_float2(vx, vy);
}

// ---- hs2[row,:] = (h[row,:] @ W2) * dinv[row]  (h = g_agg1, hs2 -> g_hs1) ----
__global__ void gemm2_kernel(const void* __restrict__ W2, int N) {
    __shared__ float Ws[HID_DIM * OUT_DIM];  // 32 KB
    __shared__ float hsh[4 * HID_DIM];
    int t = threadIdx.x;
    int f32 = g_in_f32;
    for (int i = t; i < HID_DIM * OUT_DIM; i += 256) Ws[i] = loadx(W2, i, f32);
    int row0 = blockIdx.x * 4;
    for (int i = t; i < 4 * HID_DIM; i += 256) {
        int r = row0 + (i >> 7);
        hsh[i] = (r < N) ? g_agg1[r * HID_DIM + (i & (HID_DIM - 1))] : 0.f;
    }
    __syncthreads();
    int r = t >> 6;
    int col = t & 63;
    int row = row0 + r;
    if (row >= N) return;
    float acc = 0.f;
#pragma unroll
    for (int k = 0; k < HID_DIM; k++) acc = fmaf(hsh[r * HID_DIM + k], Ws[k * OUT_DIM + col], acc);
    g_hs1[row * OUT_DIM + col] = acc * g_dinv[row];
}

// ---- layer-2 aggregation: wave per node, float/lane; fused bias + store ----
__global__ void agg2_kernel(const void* __restrict__ b2, void* __restrict__ out, int N) {
    int wid = (blockIdx.x * blockDim.x + threadIdx.x) >> 6;
    if (wid >= N) return;
    int lane = threadIdx.x & 63;
    const float* hs = g_hs1;  // row = 64 floats
    float acc = hs[wid * 64 + lane];  // self-loop term
    float acc2 = 0.f;
    int beg = g_rowptr[wid], end = g_rowptr[wid + 1];
    int e = beg;
    for (; e + 2 <= end; e += 2) {
        int s0 = g_csr[e], s1 = g_csr[e + 1];
        acc += hs[s0 * 64 + lane];
        acc2 += hs[s1 * 64 + lane];
    }
    if (e < end) acc += hs[g_csr[e] * 64 + lane];
    acc += acc2;
    int f32 = g_in_f32;
    float v = acc * g_dinv[wid] + loadx(b2, lane, f32);
    if (f32) ((float*)out)[wid * 64 + lane] = v;
    else ((__hip_bfloat16*)out)[wid * 64 + lane] = __float2bfloat16(v);
}

extern "C" void kernel_launch(void* const* d_in, const int* in_sizes, int n_in,
                              void* d_out, int out_size, void* d_ws, size_t ws_size,
                              hipStream_t stream) {
    const void* z  = d_in[0];
    const void* ei = d_in[1];
    const void* W1 = d_in[2];
    const void* b1 = d_in[3];
    const void* W2 = d_in[4];
    const void* b2 = d_in[5];

    const int N = in_sizes[0] / IN_DIM;  // 50000
    const int E = in_sizes[1] / 2;       // 800000

    detect_kernel<<<1, 256, 0, stream>>>((const unsigned short*)z, (const unsigned int*)ei, E);
    convert_kernel<<<(E + 255) / 256, 256, 0, stream>>>(ei, E);
    deg_kernel<<<(E + 255) / 256, 256, 0, stream>>>(E);
    scan_kernel<<<1, SCAN_T, 0, stream>>>(N, E);
    scatter_kernel<<<(E + 255) / 256, 256, 0, stream>>>(E);

    gemm1_kernel<<<(N + 1) / 2, 256, 0, stream>>>(z, W1, N);
    agg1_kernel<<<(N * 64 + 255) / 256, 256, 0, stream>>>(b1, N);

    gemm2_kernel<<<(N + 3) / 4, 256, 0, stream>>>(W2, N);
    agg2_kernel<<<(N * 64 + 255) / 256, 256, 0, stream>>>(b2, d_out, N);
}